// Round 7
// baseline (610.417 us; speedup 1.0000x reference)
//
#include <hip/hip_runtime.h>
#include <hip/hip_bf16.h>
#include <cstdio>

// Problem dims
#define BS   2
#define LL   2048
#define HH   8
#define PP   64
#define NQ   300          // d_state / num queries
#define NPAD 320          // padded n
#define NG   5            // n-groups of 64 lanes (5*64 = 320)
#define PJ   8            // p's per wave (8 waves * 8 = 64 = PP)
#define TT   64           // chunk length
#define NCH  32           // L / TT
#define DI   512
#define DKEY 1034

// ---------------------------------------------------------------------------
// Generic GEMM-NT: C[m,n] = sum_k A[m*lda+k] * B[n*ldb+k]  (64x64 tile)
// ---------------------------------------------------------------------------
__global__ __launch_bounds__(256) void gemm_nt(
    const float* __restrict__ A, const float* __restrict__ Bm, float* __restrict__ C,
    int M, int N, int K, int lda, int ldb, int ldc)
{
    __shared__ float As[16][68];
    __shared__ float Bs[16][68];
    const int tid = threadIdx.x;
    const int tx = tid & 15, ty = tid >> 4;
    const int m0 = blockIdx.x * 64, n0 = blockIdx.y * 64;
    const int lr = tid >> 2, lk = (tid & 3) << 2;
    float acc[4][4] = {};
    for (int k0 = 0; k0 < K; k0 += 16) {
        float4 av = make_float4(0.f,0.f,0.f,0.f), bv = make_float4(0.f,0.f,0.f,0.f);
        int am = m0 + lr;
        if (am < M) av = *(const float4*)(A + (size_t)am * lda + k0 + lk);
        int bn = n0 + lr;
        if (bn < N) bv = *(const float4*)(Bm + (size_t)bn * ldb + k0 + lk);
        __syncthreads();
        As[lk+0][lr] = av.x; As[lk+1][lr] = av.y; As[lk+2][lr] = av.z; As[lk+3][lr] = av.w;
        Bs[lk+0][lr] = bv.x; Bs[lk+1][lr] = bv.y; Bs[lk+2][lr] = bv.z; Bs[lk+3][lr] = bv.w;
        __syncthreads();
        #pragma unroll
        for (int kk = 0; kk < 16; ++kk) {
            float a0 = As[kk][ty*4+0], a1 = As[kk][ty*4+1], a2 = As[kk][ty*4+2], a3 = As[kk][ty*4+3];
            float b0 = Bs[kk][tx*4+0], b1 = Bs[kk][tx*4+1], b2 = Bs[kk][tx*4+2], b3 = Bs[kk][tx*4+3];
            acc[0][0] = fmaf(a0,b0,acc[0][0]); acc[0][1] = fmaf(a0,b1,acc[0][1]);
            acc[0][2] = fmaf(a0,b2,acc[0][2]); acc[0][3] = fmaf(a0,b3,acc[0][3]);
            acc[1][0] = fmaf(a1,b0,acc[1][0]); acc[1][1] = fmaf(a1,b1,acc[1][1]);
            acc[1][2] = fmaf(a1,b2,acc[1][2]); acc[1][3] = fmaf(a1,b3,acc[1][3]);
            acc[2][0] = fmaf(a2,b0,acc[2][0]); acc[2][1] = fmaf(a2,b1,acc[2][1]);
            acc[2][2] = fmaf(a2,b2,acc[2][2]); acc[2][3] = fmaf(a2,b3,acc[2][3]);
            acc[3][0] = fmaf(a3,b0,acc[3][0]); acc[3][1] = fmaf(a3,b1,acc[3][1]);
            acc[3][2] = fmaf(a3,b2,acc[3][2]); acc[3][3] = fmaf(a3,b3,acc[3][3]);
        }
    }
    #pragma unroll
    for (int i = 0; i < 4; ++i) {
        int m = m0 + ty*4 + i;
        if (m >= M) continue;
        #pragma unroll
        for (int j = 0; j < 4; ++j) {
            int n = n0 + tx*4 + j;
            if (n < N) C[(size_t)m * ldc + n] = acc[i][j];
        }
    }
}

// ---------------------------------------------------------------------------
// Bigger GEMM-NT: 128x64 tile, 256 threads, 8x4 micro-tile.
// ---------------------------------------------------------------------------
__global__ __launch_bounds__(256) void gemm_nt_big(
    const float* __restrict__ A, const float* __restrict__ Bm, float* __restrict__ C,
    int M, int N, int K, int lda, int ldb, int ldc)
{
    __shared__ float As[16][132];
    __shared__ float Bs[16][68];
    const int tid = threadIdx.x;
    const int tx = tid & 15, ty = tid >> 4;
    const int m0 = blockIdx.x * 128, n0 = blockIdx.y * 64;
    const int lr = tid >> 2, lk = (tid & 3) << 2;
    float acc[8][4] = {};
    for (int k0 = 0; k0 < K; k0 += 16) {
        float4 a0v = make_float4(0.f,0.f,0.f,0.f), a1v = a0v, bv = a0v;
        int am0 = m0 + lr, am1 = m0 + 64 + lr;
        if (am0 < M) a0v = *(const float4*)(A + (size_t)am0 * lda + k0 + lk);
        if (am1 < M) a1v = *(const float4*)(A + (size_t)am1 * lda + k0 + lk);
        int bn = n0 + lr;
        if (bn < N) bv = *(const float4*)(Bm + (size_t)bn * ldb + k0 + lk);
        __syncthreads();
        As[lk+0][lr] = a0v.x; As[lk+1][lr] = a0v.y; As[lk+2][lr] = a0v.z; As[lk+3][lr] = a0v.w;
        As[lk+0][64+lr] = a1v.x; As[lk+1][64+lr] = a1v.y; As[lk+2][64+lr] = a1v.z; As[lk+3][64+lr] = a1v.w;
        Bs[lk+0][lr] = bv.x; Bs[lk+1][lr] = bv.y; Bs[lk+2][lr] = bv.z; Bs[lk+3][lr] = bv.w;
        __syncthreads();
        #pragma unroll
        for (int kk = 0; kk < 16; ++kk) {
            float a[8], b[4];
            #pragma unroll
            for (int i = 0; i < 8; ++i) a[i] = As[kk][ty*8+i];
            #pragma unroll
            for (int j = 0; j < 4; ++j) b[j] = Bs[kk][tx*4+j];
            #pragma unroll
            for (int i = 0; i < 8; ++i)
                #pragma unroll
                for (int j = 0; j < 4; ++j)
                    acc[i][j] = fmaf(a[i], b[j], acc[i][j]);
        }
    }
    #pragma unroll
    for (int i = 0; i < 8; ++i) {
        int m = m0 + ty*8 + i;
        if (m >= M) continue;
        #pragma unroll
        for (int j = 0; j < 4; ++j) {
            int n = n0 + tx*4 + j;
            if (n < N) C[(size_t)m * ldc + n] = acc[i][j];
        }
    }
}

// ---------------------------------------------------------------------------
// dt / B / C precompute -> pairs {a=exp(dt*A), u=dt*B} per (b,h,l,n), C per
// (b,l,n), padded to NPAD (pads: a=1,u=0,c=0).
// ---------------------------------------------------------------------------
__global__ __launch_bounds__(256) void dtbc_kernel(
    const float* __restrict__ dist, const float* __restrict__ zx,
    const float* __restrict__ W_bc, const float* __restrict__ W_dt,
    const float* __restrict__ dt_bias, const float* __restrict__ A_log,
    float2* __restrict__ pairs, float* __restrict__ Cc)
{
    const int r = blockIdx.x;           // b*LL + l
    const int b = r >> 11, l = r & 2047;
    const int tid = threadIdx.x;
    const float bb = zx[(size_t)r*DKEY + 1024];
    const float cb = zx[(size_t)r*DKEY + 1025];
    #pragma unroll
    for (int rep = 0; rep < 2; ++rep) {
        int n = rep*256 + tid;
        if (n >= NPAD) continue;
        if (n < NQ) {
            const float4* dp = (const float4*)(dist + ((size_t)r*NQ + n)*16);
            float d[16];
            #pragma unroll
            for (int j = 0; j < 4; ++j) {
                float4 v = dp[j];
                d[4*j+0]=v.x; d[4*j+1]=v.y; d[4*j+2]=v.z; d[4*j+3]=v.w;
            }
            float Bv = bb, Cv = cb;
            #pragma unroll
            for (int j = 0; j < 16; ++j) {
                Bv = fmaf(d[j], W_bc[j],     Bv);
                Cv = fmaf(d[j], W_bc[16+j],  Cv);
            }
            Cc[(size_t)r*NPAD + n] = Cv;
            #pragma unroll
            for (int h = 0; h < HH; ++h) {
                float s = zx[(size_t)r*DKEY + 1026 + h] + dt_bias[h];
                #pragma unroll
                for (int j = 0; j < 16; ++j) s = fmaf(d[j], W_dt[h*16+j], s);
                float dtv = (s > 20.f) ? s : log1pf(expf(s));
                float Ah = -expf(A_log[h]);
                pairs[((size_t)(b*HH+h)*LL + l)*NPAD + n] = make_float2(expf(dtv*Ah), dtv*Bv);
            }
        } else {
            Cc[(size_t)r*NPAD + n] = 0.f;
            #pragma unroll
            for (int h = 0; h < HH; ++h)
                pairs[((size_t)(b*HH+h)*LL + l)*NPAD + n] = make_float2(1.f, 0.f);
        }
    }
}

// ---------------------------------------------------------------------------
// Full-chunk decay products: Adec[bh][c][n] = prod over TT steps (dir-shared).
// ---------------------------------------------------------------------------
__global__ __launch_bounds__(320) void adec_kernel(
    const float2* __restrict__ pairs, float* __restrict__ Adec)
{
    const int bid = blockIdx.x;        // c + NCH*bh, 512 total
    const int c = bid & (NCH-1), bh = bid >> 5;
    const int n = threadIdx.x;
    const float2* pr = pairs + ((size_t)bh*LL + c*TT)*NPAD + n;
    float prod = 1.f;
    #pragma unroll 8
    for (int t = 0; t < TT; ++t) prod *= pr[(size_t)t*NPAD].x;
    Adec[((size_t)bh*NCH + c)*NPAD + n] = prod;
}

// ---------------------------------------------------------------------------
// Transpose init states: projT[(b*8+h)*64+p][n] = proj[b*NQ+n][h*64+p] (0-pad)
// ---------------------------------------------------------------------------
__global__ __launch_bounds__(320) void transpose_proj(
    const float* __restrict__ proj, float* __restrict__ projT)
{
    const int bid = blockIdx.x;       // (b*8+h)*64 + p
    const int p = bid & 63, h = (bid >> 6) & 7, b = bid >> 9;
    const int n = threadIdx.x;
    float v = 0.f;
    if (n < NQ) v = proj[((size_t)(b*NQ + n))*DI + h*64 + p];
    projT[(size_t)bid*NPAD + n] = v;
}

// ---------------------------------------------------------------------------
// 64-lane reduce-scatter: input yl[8] per lane, output: lane L holds the
// 64-lane sum of index j = L&7.
// ---------------------------------------------------------------------------
__device__ __forceinline__ float reduce8x64(const float yl[8], int L)
{
    const bool h1 = (L & 1), h2 = (L & 2), h4 = (L & 4);
    float t0 = (h1 ? yl[1] : yl[0]) + __shfl_xor(h1 ? yl[0] : yl[1], 1, 64);
    float t1 = (h1 ? yl[3] : yl[2]) + __shfl_xor(h1 ? yl[2] : yl[3], 1, 64);
    float t2 = (h1 ? yl[5] : yl[4]) + __shfl_xor(h1 ? yl[4] : yl[5], 1, 64);
    float t3 = (h1 ? yl[7] : yl[6]) + __shfl_xor(h1 ? yl[6] : yl[7], 1, 64);
    float u0 = (h2 ? t1 : t0) + __shfl_xor(h2 ? t0 : t1, 2, 64);
    float u1 = (h2 ? t3 : t2) + __shfl_xor(h2 ? t2 : t3, 2, 64);
    float v  = (h4 ? u1 : u0) + __shfl_xor(h4 ? u0 : u1, 4, 64);
    v += __shfl_xor(v, 8, 64);
    v += __shfl_xor(v, 16, 64);
    v += __shfl_xor(v, 32, 64);
    return v;
}

// ---------------------------------------------------------------------------
// Sweep A: intra-chunk scan, lane = n. 1024 blocks = (dir,b,h,chunk of 64),
// 512 thr -> 4 blocks/CU (full occupancy). Wave w owns p in [w*8, w*8+8).
// ---------------------------------------------------------------------------
__global__ __launch_bounds__(512, 4) void sweepA(
    const float2* __restrict__ pairs, const float* __restrict__ Cc,
    const float* __restrict__ zx,
    float* __restrict__ Sloc, float* __restrict__ yFa, float* __restrict__ yBa)
{
    const int bid = blockIdx.x;
    const int c = bid & (NCH-1), h = (bid >> 5) & 7, b = (bid >> 8) & 1, dir = bid >> 9;
    const int tid = threadIdx.x;
    const int L = tid & 63, w = tid >> 6;
    float* __restrict__ ybuf = dir ? yBa : yFa;

    __shared__ float xs[TT*64];      // 16 KB: x[t][p] for the whole chunk

    for (int idx = tid; idx < TT*64; idx += 512) {
        int t = idx >> 6, pp = idx & 63;
        int ls = c*TT + t;
        int l = dir ? (LL-1-ls) : ls;
        xs[idx] = zx[(size_t)(b*LL + l)*DKEY + 512 + h*64 + pp];
    }
    __syncthreads();

    const int lstart = dir ? (LL-1 - c*TT) : c*TT;
    const int lstep  = dir ? -1 : 1;
    const float2* __restrict__ pb = pairs + ((size_t)(b*HH+h)*LL + lstart)*NPAD + L;
    const float*  __restrict__ cb = Cc + ((size_t)(b*LL) + lstart)*NPAD + L;
    const ptrdiff_t pstride = (ptrdiff_t)lstep * NPAD;

    float S[NG][PJ];
    #pragma unroll
    for (int g = 0; g < NG; ++g)
        #pragma unroll
        for (int j = 0; j < PJ; ++j) S[g][j] = 0.f;

    float2 pv[2][NG]; float cv[2][NG];
    #pragma unroll
    for (int g = 0; g < NG; ++g) { pv[0][g] = pb[g*64]; cv[0][g] = cb[g*64]; }

    for (int t8 = 0; t8 < TT/8; ++t8) {
        #pragma unroll
        for (int tt = 0; tt < 8; ++tt) {
            const int t = t8*8 + tt;
            const int cur = tt & 1, nxt = cur ^ 1;
            const int tn = (t+1 < TT) ? t+1 : t;
            const float2* pn = pb + (ptrdiff_t)tn * pstride;
            const float*  cn = cb + (ptrdiff_t)tn * pstride;
            #pragma unroll
            for (int g = 0; g < NG; ++g) { pv[nxt][g] = pn[g*64]; cv[nxt][g] = cn[g*64]; }

            const float4* xp = (const float4*)&xs[(t << 6) + w*PJ];
            float4 xa = xp[0], xb2 = xp[1];
            float xv[8] = {xa.x, xa.y, xa.z, xa.w, xb2.x, xb2.y, xb2.z, xb2.w};

            float yl[8];
            #pragma unroll
            for (int j = 0; j < 8; ++j) yl[j] = 0.f;
            #pragma unroll
            for (int g = 0; g < NG; ++g) {
                const float a = pv[cur][g].x, u = pv[cur][g].y, cg = cv[cur][g];
                #pragma unroll
                for (int j = 0; j < PJ; ++j) {
                    S[g][j] = fmaf(S[g][j], a, u * xv[j]);
                    yl[j] = fmaf(S[g][j], cg, yl[j]);
                }
            }
            float v = reduce8x64(yl, L);
            if (L < 8) {
                int l = lstart + t*lstep;
                ybuf[(((size_t)(b*LL + l))*HH + h)*64 + w*PJ + L] = v;
            }
        }
    }
    // chunk-end state: Sloc[dbh][c][p][n]
    const int dbh = dir*16 + b*8 + h;
    const size_t sb = (((size_t)dbh*NCH + c)*64)*NPAD;
    #pragma unroll
    for (int g = 0; g < NG; ++g)
        #pragma unroll
        for (int j = 0; j < PJ; ++j)
            Sloc[sb + (size_t)(w*PJ + j)*NPAD + g*64 + L] = S[g][j];
}

// ---------------------------------------------------------------------------
// Inter-chunk scan IN PLACE: after this kernel, Sloc[dbh][c][p][n] holds the
// carry state BEFORE chunk c (what sweepB needs); final state -> Sfin.
// ---------------------------------------------------------------------------
__global__ __launch_bounds__(320) void chunkscan(
    float* __restrict__ Sloc, const float* __restrict__ Adec,
    const float* __restrict__ projT, float* __restrict__ Sfin)
{
    const int bid = blockIdx.x;      // dbh*64 + p
    const int p = bid & 63, dbh = bid >> 6;
    const int bh = dbh & 15, dir = dbh >> 4;
    const int n = threadIdx.x;
    float cur = projT[(size_t)(bh*64 + p)*NPAD + n];
    #pragma unroll 4
    for (int cc = 0; cc < NCH; ++cc) {
        int cF = dir ? (NCH-1-cc) : cc;
        float ad = Adec[((size_t)bh*NCH + cF)*NPAD + n];
        size_t si = ((size_t)(dbh*NCH + cc)*64 + p)*NPAD + n;
        float s = Sloc[si];
        Sloc[si] = cur;
        cur = fmaf(cur, ad, s);
    }
    Sfin[((size_t)dbh*64 + p)*NPAD + n] = cur;
}

// ---------------------------------------------------------------------------
// Sweep B: carry corrections, lane = n; accumulates into yFa/yBa (+=).
// ---------------------------------------------------------------------------
__global__ __launch_bounds__(512, 4) void sweepB(
    const float2* __restrict__ pairs, const float* __restrict__ Cc,
    const float* __restrict__ Sloc,
    float* __restrict__ yFa, float* __restrict__ yBa)
{
    const int bid = blockIdx.x;
    const int c = bid & (NCH-1), h = (bid >> 5) & 7, b = (bid >> 8) & 1, dir = bid >> 9;
    const int tid = threadIdx.x;
    const int L = tid & 63, w = tid >> 6;
    float* __restrict__ ybuf = dir ? yBa : yFa;

    const int dbh = dir*16 + b*8 + h;
    const size_t cb0 = (((size_t)dbh*NCH + c)*64)*NPAD;
    float cr[NG][PJ];
    #pragma unroll
    for (int g = 0; g < NG; ++g)
        #pragma unroll
        for (int j = 0; j < PJ; ++j)
            cr[g][j] = Sloc[cb0 + (size_t)(w*PJ + j)*NPAD + g*64 + L];

    const int lstart = dir ? (LL-1 - c*TT) : c*TT;
    const int lstep  = dir ? -1 : 1;
    const float2* __restrict__ pb = pairs + ((size_t)(b*HH+h)*LL + lstart)*NPAD + L;
    const float*  __restrict__ cb = Cc + ((size_t)(b*LL) + lstart)*NPAD + L;
    const ptrdiff_t pstride = (ptrdiff_t)lstep * NPAD;

    float2 pv[2][NG]; float cv[2][NG];
    #pragma unroll
    for (int g = 0; g < NG; ++g) { pv[0][g] = pb[g*64]; cv[0][g] = cb[g*64]; }

    for (int t8 = 0; t8 < TT/8; ++t8) {
        #pragma unroll
        for (int tt = 0; tt < 8; ++tt) {
            const int t = t8*8 + tt;
            const int cur = tt & 1, nxt = cur ^ 1;
            const int tn = (t+1 < TT) ? t+1 : t;
            const float2* pn = pb + (ptrdiff_t)tn * pstride;
            const float*  cn = cb + (ptrdiff_t)tn * pstride;
            #pragma unroll
            for (int g = 0; g < NG; ++g) { pv[nxt][g] = pn[g*64]; cv[nxt][g] = cn[g*64]; }

            float yl[8];
            #pragma unroll
            for (int j = 0; j < 8; ++j) yl[j] = 0.f;
            #pragma unroll
            for (int g = 0; g < NG; ++g) {
                const float a = pv[cur][g].x, cg = cv[cur][g];
                #pragma unroll
                for (int j = 0; j < PJ; ++j) {
                    cr[g][j] *= a;
                    yl[j] = fmaf(cr[g][j], cg, yl[j]);
                }
            }
            float v = reduce8x64(yl, L);
            if (L < 8) {
                int l = lstart + t*lstep;
                size_t yi = (((size_t)(b*LL + l))*HH + h)*64 + w*PJ + L;
                ybuf[yi] += v;
            }
        }
    }
}

// ---------------------------------------------------------------------------
// Gated RMSNorm: g = (0.5*(yFa+yBa) + x*D)*silu(z)
// ---------------------------------------------------------------------------
__global__ __launch_bounds__(256) void gate_rms(
    const float* __restrict__ zx,
    const float* __restrict__ yFa, const float* __restrict__ yBa,
    const float* __restrict__ Dp,
    const float* __restrict__ knw, float* __restrict__ kfn)
{
    const int r = blockIdx.x, tid = threadIdx.x;
    __shared__ float part[4];
    float g[2];
    #pragma unroll
    for (int rep = 0; rep < 2; ++rep) {
        int dcol = rep*256 + tid;
        size_t yi = (size_t)r*DI + dcol;
        float zv = zx[(size_t)r*DKEY + dcol];
        float xv = zx[(size_t)r*DKEY + 512 + dcol];
        float yv = 0.5f*(yFa[yi] + yBa[yi]) + xv * Dp[dcol >> 6];
        float sig = 1.f / (1.f + expf(-zv));
        g[rep] = yv * (zv * sig);
    }
    float ss = g[0]*g[0] + g[1]*g[1];
    #pragma unroll
    for (int o = 32; o; o >>= 1) ss += __shfl_xor(ss, o, 64);
    if ((tid & 63) == 0) part[tid >> 6] = ss;
    __syncthreads();
    float tot = part[0] + part[1] + part[2] + part[3];
    float scale = rsqrtf(tot * (1.f/512.f) + 1e-5f);
    #pragma unroll
    for (int rep = 0; rep < 2; ++rep) {
        int dcol = rep*256 + tid;
        kfn[(size_t)r*DI + dcol] = g[rep] * scale * knw[dcol];
    }
}

// ---------------------------------------------------------------------------
// Final-state LayerNorm from Sfin[dbh][p][q] (fwd+bwd averaged)
// ---------------------------------------------------------------------------
__global__ __launch_bounds__(512) void state_ln(
    const float* __restrict__ Sfin, const float* __restrict__ qw,
    const float* __restrict__ qb, float* __restrict__ lastn)
{
    const int row = blockIdx.x;          // b*NQ + q
    const int b = row / NQ, q = row % NQ;
    const int tid = threadIdx.x;         // 512
    const int h = tid >> 6, p = tid & 63;
    __shared__ float pm[8], pv[8];
    size_t iF = ((size_t)((b*8 + h)*64) + p)*NPAD + q;
    size_t iB = ((size_t)((16 + b*8 + h)*64) + p)*NPAD + q;
    float v = 0.5f * (Sfin[iF] + Sfin[iB]);
    float s1 = v, s2 = v*v;
    #pragma unroll
    for (int o = 32; o; o >>= 1) { s1 += __shfl_xor(s1, o, 64); s2 += __shfl_xor(s2, o, 64); }
    if ((tid & 63) == 0) { pm[tid >> 6] = s1; pv[tid >> 6] = s2; }
    __syncthreads();
    float m = 0.f, s = 0.f;
    #pragma unroll
    for (int i = 0; i < 8; ++i) { m += pm[i]; s += pv[i]; }
    m *= (1.f/512.f);
    s = s*(1.f/512.f) - m*m;
    lastn[(size_t)row*DI + tid] = (v - m)*rsqrtf(s + 1e-5f)*qw[tid] + qb[tid];
}

// ---------------------------------------------------------------------------
extern "C" void kernel_launch(void* const* d_in, const int* in_sizes, int n_in,
                              void* d_out, int out_size, void* d_ws, size_t ws_size,
                              hipStream_t stream)
{
    const float* in_key    = (const float*)d_in[0];
    const float* in_query  = (const float*)d_in[1];
    const float* dist      = (const float*)d_in[2];
    const float* W_key     = (const float*)d_in[3];
    const float* W_query   = (const float*)d_in[4];
    const float* W_bc      = (const float*)d_in[5];
    const float* W_dt      = (const float*)d_in[6];
    const float* dt_bias   = (const float*)d_in[7];
    const float* A_log     = (const float*)d_in[8];
    const float* Dp        = (const float*)d_in[9];
    const float* W_out_key = (const float*)d_in[10];
    const float* W_out_qry = (const float*)d_in[11];
    const float* knw       = (const float*)d_in[12];
    const float* qw        = (const float*)d_in[13];
    const float* qb        = (const float*)d_in[14];
    float* out = (float*)d_out;

    float* ws = (float*)d_ws;
    size_t off = 0;
    auto alloc = [&](size_t nf) { float* pp = ws + off; off += nf; return pp; };
    float*  zx    = alloc((size_t)4096*DKEY);             // 4.24M floats
    float*  proj  = alloc((size_t)600*DI);                // 0.31M
    float*  projT = alloc((size_t)1024*NPAD);             // 0.33M
    float2* pairs = (float2*)alloc((size_t)16*LL*NPAD*2); // 21.0M
    float*  Cc    = alloc((size_t)BS*LL*NPAD);            // 1.31M
    float*  Sloc  = alloc((size_t)32*NCH*64*NPAD);        // 20.97M (becomes carries; reused for kfn/lastn)
    float*  Adec  = alloc((size_t)16*NCH*NPAD);           // 0.16M
    float*  Sfin  = alloc((size_t)32*64*NPAD);            // 0.66M
    float*  yFa   = alloc((size_t)BS*LL*DI);              // 2.1M
    float*  yBa   = alloc((size_t)BS*LL*DI);              // 2.1M
    float*  kfn   = Sloc;                                  // alias (dead after sweepB)
    float*  lastn = Sloc + (size_t)4096*DI;
    if (off * sizeof(float) > ws_size) {
        fprintf(stderr, "kernel_launch: workspace too small: need %zu bytes, have %zu\n",
                off * sizeof(float), ws_size);
        return;
    }

    dim3 blk(256);
    // K1: zxbcdt = in_key @ W_key^T   [4096 x 1034]
    gemm_nt_big<<<dim3(32, 17), blk, 0, stream>>>(in_key, W_key, zx, 4096, DKEY, 256, 256, 256, DKEY);
    // K2: init = in_query @ W_query^T  [600 x 512] + transpose
    gemm_nt<<<dim3(10, 8), blk, 0, stream>>>(in_query, W_query, proj, 600, DI, 256, 256, 256, DI);
    transpose_proj<<<1024, dim3(320), 0, stream>>>(proj, projT);
    // K3: coefficient precompute
    dtbc_kernel<<<4096, blk, 0, stream>>>(dist, zx, W_bc, W_dt, dt_bias, A_log, pairs, Cc);
    // K3b: full-chunk decay products (dir-shared)
    adec_kernel<<<512, dim3(320), 0, stream>>>(pairs, Adec);
    // K4: intra-chunk scans (lane = n, 4 blocks/CU)
    sweepA<<<1024, dim3(512), 0, stream>>>(pairs, Cc, zx, Sloc, yFa, yBa);
    // K5: inter-chunk scan (in place; Sloc becomes per-chunk carries)
    chunkscan<<<2048, dim3(320), 0, stream>>>(Sloc, Adec, projT, Sfin);
    // K6: carry corrections accumulated into y
    sweepB<<<1024, dim3(512), 0, stream>>>(pairs, Cc, Sloc, yFa, yBa);
    // K7: gated RMSNorm + out_key projection
    gate_rms<<<4096, blk, 0, stream>>>(zx, yFa, yBa, Dp, knw, kfn);
    gemm_nt<<<dim3(64, 4), blk, 0, stream>>>(kfn, W_out_key, out, 4096, 256, DI, DI, DI, 256);
    // K8: final-state LayerNorm + out_query projection
    state_ln<<<600, dim3(512), 0, stream>>>(Sfin, qw, qb, lastn);
    gemm_nt<<<dim3(10, 4), blk, 0, stream>>>(lastn, W_out_qry, out + (size_t)4096*256, 600, 256, DI, DI, DI, 256);
}